// Round 1
// baseline (2273.446 us; speedup 1.0000x reference)
//
#include <hip/hip_runtime.h>

// HMM forward (CgpHmmCell): B=512, T=4096, S=64, M=125
// Inputs: x [B,T,M] fp32 one-hot, I [1,S], A [S,S], Bm [M,S]. Out: loglik [B,1].
//
// Phase 1 (extract_obs): recover obs[b,t] = argmax_m x[b,t,m] by linear float4
//   scan of the 1.07 GB one-hot tensor -> 2 MB of uint8 indices in d_ws.
// Phase 2 (hmm_scan): one wave per sequence, lane j owns state j.
//   Matvec alpha@A via 64x (v_readlane broadcast + v_fmac with per-lane A column).
//   Rescale each step by surrogate c = w[lane0] (readfirstlane) instead of the
//   exact sum -- ll = sum log c_t + log(sum_j w_final[j]) is exact for ANY c>0,
//   so no per-step cross-lane allreduce is needed (one allreduce at the end).

#define BATCH 512
#define T 4096
#define S 64
#define M 125

// ---------------- Phase 1: one-hot -> byte index ----------------
__global__ __launch_bounds__(256) void extract_obs(const float4* __restrict__ x4,
                                                   unsigned char* __restrict__ obs) {
    const long long n4 = (long long)BATCH * T * M / 4;  // 65,536,000 float4s
    long long stride = (long long)gridDim.x * blockDim.x;
    for (long long i = (long long)blockIdx.x * blockDim.x + threadIdx.x; i < n4; i += stride) {
        float4 v = x4[i];
        // each component may belong to a different row (125 not divisible by 4)
        if (v.x != 0.0f || v.y != 0.0f || v.z != 0.0f || v.w != 0.0f) {
            long long e = i * 4;
            if (v.x != 0.0f) { long long r = (e + 0) / M; obs[r] = (unsigned char)(e + 0 - r * M); }
            if (v.y != 0.0f) { long long r = (e + 1) / M; obs[r] = (unsigned char)(e + 1 - r * M); }
            if (v.z != 0.0f) { long long r = (e + 2) / M; obs[r] = (unsigned char)(e + 2 - r * M); }
            if (v.w != 0.0f) { long long r = (e + 3) / M; obs[r] = (unsigned char)(e + 3 - r * M); }
        }
    }
}

// ---------------- Phase 2: sequential scan, one wave per sequence ----------------
__device__ __forceinline__ void hmm_step(int o, int lane, float& a, double& L,
                                         const float (&Acol)[S], const float* BmL) {
    // R[j] = sum_i alpha[i] * A[i][j]; alpha broadcast lane->SGPR via readlane.
    float R0 = 0.f, R1 = 0.f, R2 = 0.f, R3 = 0.f;
    unsigned int au = __float_as_uint(a);
#pragma unroll
    for (int i = 0; i < S; i += 4) {
        float s0 = __uint_as_float(__builtin_amdgcn_readlane(au, i + 0));
        float s1 = __uint_as_float(__builtin_amdgcn_readlane(au, i + 1));
        float s2 = __uint_as_float(__builtin_amdgcn_readlane(au, i + 2));
        float s3 = __uint_as_float(__builtin_amdgcn_readlane(au, i + 3));
        R0 = fmaf(s0, Acol[i + 0], R0);
        R1 = fmaf(s1, Acol[i + 1], R1);
        R2 = fmaf(s2, Acol[i + 2], R2);
        R3 = fmaf(s3, Acol[i + 3], R3);
    }
    float R = (R0 + R1) + (R2 + R3);
    float E = BmL[(o << 6) + lane];     // Bm[o][lane], conflict-free (2 lanes/bank = free)
    float w = R * E;
    // surrogate scaling: any positive c keeps ll exact; pick lane0's value.
    float c = __uint_as_float(__builtin_amdgcn_readfirstlane(__float_as_uint(w)));
    L += (double)__log2f(c);
    a = w * __builtin_amdgcn_rcpf(c);
}

__global__ __launch_bounds__(64) void hmm_scan(const unsigned char* __restrict__ obs,
                                               const float* __restrict__ I,
                                               const float* __restrict__ A,
                                               const float* __restrict__ Bm,
                                               float* __restrict__ out) {
    __shared__ float BmL[M * S];  // 32000 B
    const int lane = threadIdx.x;  // 0..63
    for (int i = lane; i < M * S; i += 64) BmL[i] = Bm[i];

    float Acol[S];  // column `lane` of A, in registers
#pragma unroll
    for (int i = 0; i < S; ++i) Acol[i] = A[i * S + lane];
    __syncthreads();

    const int seq = blockIdx.x;
    const unsigned char* ob = obs + (size_t)seq * T;

    // t = 0: w = Bm[o0] * I
    unsigned long long pack = *(const unsigned long long*)(ob);
    int o0 = (int)(pack & 255ull);
    pack >>= 8;
    float w = BmL[(o0 << 6) + lane] * I[lane];
    float c = __uint_as_float(__builtin_amdgcn_readfirstlane(__float_as_uint(w)));
    double L = (double)__log2f(c);
    float a = w * __builtin_amdgcn_rcpf(c);

    // t = 1..7 from the first pack
#pragma unroll
    for (int k = 1; k < 8; ++k) {
        int o = (int)(pack & 255ull);
        pack >>= 8;
        hmm_step(o, lane, a, L, Acol, BmL);
    }

    // t = 8..T-1, 8 steps per uint64 of obs bytes, prefetched one block ahead
    unsigned long long p = *(const unsigned long long*)(ob + 8);
    for (int t8 = 8; t8 < T; t8 += 8) {
        unsigned long long np = 0ull;
        if (t8 + 8 < T) np = *(const unsigned long long*)(ob + t8 + 8);
#pragma unroll
        for (int k = 0; k < 8; ++k) {
            int o = (int)(p & 255ull);
            p >>= 8;
            hmm_step(o, lane, a, L, Acol, BmL);
        }
        p = np;
    }

    // final exact reduction of the carried vector (once, not per step)
    float s = a;
#pragma unroll
    for (int off = 32; off; off >>= 1) s += __shfl_xor(s, off);
    if (lane == 0)
        out[seq] = (float)((L + (double)__log2f(s)) * 0.6931471805599453);
}

extern "C" void kernel_launch(void* const* d_in, const int* in_sizes, int n_in,
                              void* d_out, int out_size, void* d_ws, size_t ws_size,
                              hipStream_t stream) {
    const float* x  = (const float*)d_in[0];   // [B,T,M] one-hot
    const float* I  = (const float*)d_in[1];   // [1,S]
    const float* A  = (const float*)d_in[2];   // [S,S]
    const float* Bm = (const float*)d_in[3];   // [M,S]
    float* out = (float*)d_out;                // [B,1]
    unsigned char* obs = (unsigned char*)d_ws; // B*T = 2 MB of uint8

    // Phase 1: 1.07 GB linear read, fully coalesced float4
    extract_obs<<<65536, 256, 0, stream>>>((const float4*)x, obs);
    // Phase 2: 512 waves, one per sequence
    hmm_scan<<<BATCH, 64, 0, stream>>>(obs, I, A, Bm, out);
}